// Round 8
// baseline (311.798 us; speedup 1.0000x reference)
//
#include <hip/hip_runtime.h>
#include <math.h>

#define B    256
#define I    1152
#define O    10
#define DIN  8
#define DOUT 16
#define OE   160          // O*DOUT
#define XROW 9216         // I*DIN (K of the s-GEMM, M of the g-GEMM)
#define WROW 1280         // O*DIN*DOUT (= OE*DIN, Wt row length)
#define PSPLIT 72         // split-K partials (now reduced via atomics)
#define CHUNK  16         // i per spart block
#define SI     8          // i per staging round (K-window 64)
#define GRID   288        // 4*PSPLIT blocks; co-resident (launch_bounds(256,2))

#define WPREP_JOBS 720    // I*OE/256

typedef __attribute__((ext_vector_type(8))) short short8;
typedef __attribute__((ext_vector_type(4))) float floatx4;

// sc1 store/load: bypass per-XCD L2, served at the coherence point (L3).
// WRITERS of cross-stage data use AS; READERS use plain loads (L2-cacheable:
// within a run each buffer has a single write phase before its first read,
// and the kernel-entry acquire fence invalidates lines from previous runs).
#define AL(p)    __hip_atomic_load((p),      __ATOMIC_RELAXED, __HIP_MEMORY_SCOPE_AGENT)
#define AS(p, v) __hip_atomic_store((p), (v), __ATOMIC_RELAXED, __HIP_MEMORY_SCOPE_AGENT)

__device__ __forceinline__ unsigned short f2bf(float f) {
    unsigned u = __builtin_bit_cast(unsigned, f);
    u += 0x7fffu + ((u >> 16) & 1u);          // RNE
    return (unsigned short)(u >> 16);
}
__device__ __forceinline__ float bf2f(unsigned short h) {
    unsigned u = ((unsigned)h) << 16;
    return __builtin_bit_cast(float, u);
}

// ---------------------------------------------------------------------------
// FULL barrier (one-time, after prep): flushes plain-stored prep outputs.
// ---------------------------------------------------------------------------
__device__ __forceinline__ void gbar_full(unsigned* cnt, unsigned* gen)
{
    __syncthreads();
    if (threadIdx.x == 0) {
        __builtin_amdgcn_fence(__ATOMIC_RELEASE, "agent");   // wbl2
        unsigned g = __hip_atomic_load(gen, __ATOMIC_RELAXED, __HIP_MEMORY_SCOPE_AGENT);
        unsigned a = __hip_atomic_fetch_add(cnt, 1u, __ATOMIC_RELAXED, __HIP_MEMORY_SCOPE_AGENT);
        if (a == GRID - 1u) {
            __hip_atomic_store(cnt, 0u, __ATOMIC_RELAXED, __HIP_MEMORY_SCOPE_AGENT);
            __hip_atomic_store(gen, g + 1u, __ATOMIC_RELAXED, __HIP_MEMORY_SCOPE_AGENT);
        } else {
            unsigned spins = 0;
            while (__hip_atomic_load(gen, __ATOMIC_RELAXED, __HIP_MEMORY_SCOPE_AGENT) == g) {
                __builtin_amdgcn_s_sleep(4);
                if (++spins > (1u << 20)) break;             // failsafe
            }
        }
        __builtin_amdgcn_fence(__ATOMIC_ACQUIRE, "agent");   // inv
    }
    __syncthreads();
}

// ---------------------------------------------------------------------------
// LIGHT barrier (steady state): no cache-wide fences. Writer side: the
// __syncthreads() drains vmcnt(0), so all sc1 stores / device atomics are
// at the coherence point before arrival. Reader side: cross-stage reads are
// either sc1 or first-touch plain loads (no stale L2 copies within a run).
// ---------------------------------------------------------------------------
__device__ __forceinline__ void gbar_light(unsigned* cnt, unsigned* gen)
{
    __syncthreads();
    if (threadIdx.x == 0) {
        unsigned g = __hip_atomic_load(gen, __ATOMIC_RELAXED, __HIP_MEMORY_SCOPE_AGENT);
        unsigned a = __hip_atomic_fetch_add(cnt, 1u, __ATOMIC_RELAXED, __HIP_MEMORY_SCOPE_AGENT);
        if (a == GRID - 1u) {
            __hip_atomic_store(cnt, 0u, __ATOMIC_RELAXED, __HIP_MEMORY_SCOPE_AGENT);
            __hip_atomic_store(gen, g + 1u, __ATOMIC_RELEASE, __HIP_MEMORY_SCOPE_AGENT);
        } else {
            unsigned spins = 0;
            while (__hip_atomic_load(gen, __ATOMIC_RELAXED, __HIP_MEMORY_SCOPE_AGENT) == g) {
                __builtin_amdgcn_s_sleep(4);
                if (++spins > (1u << 20)) break;             // failsafe
            }
        }
    }
    __syncthreads();
}

// ---------------------------------------------------------------------------
// STAGE: prep (one-time). W -> Wt[i][oe][d] fp32; x -> xTh/xTl[(i,d)][b]
// bf16 hi/lo (g-GEMM A); x -> xh/xl[b][k] bf16 hi/lo (spart A preload);
// zero the 3 per-iteration s accumulators via sc1 (no dirty-L2 residue).
// ---------------------------------------------------------------------------
__device__ __forceinline__ void stage_prep(
    int bid, int t,
    const float* __restrict__ x, const float* __restrict__ W,
    float* __restrict__ Wt,
    unsigned short* __restrict__ xTh, unsigned short* __restrict__ xTl,
    unsigned short* __restrict__ xh,  unsigned short* __restrict__ xl,
    float* __restrict__ sbase)
{
#pragma unroll
    for (int r = 0; r < 3; ++r) {
        int job = bid + GRID * r;
        if (job < WPREP_JOBS) {
            int g  = job * 256 + t;               // (i, oe) pair
            int i  = g / OE;
            int oe = g - i * OE;
            int o  = oe >> 4;
            int e  = oe & 15;
            const float* wp = W + (size_t)i * WROW + o * (DIN * DOUT) + e;
            float4 a, b;
            a.x = wp[0 * DOUT]; a.y = wp[1 * DOUT]; a.z = wp[2 * DOUT]; a.w = wp[3 * DOUT];
            b.x = wp[4 * DOUT]; b.y = wp[5 * DOUT]; b.z = wp[6 * DOUT]; b.w = wp[7 * DOUT];
            float4* dst = (float4*)(Wt + (size_t)g * 8);
            dst[0] = a;
            dst[1] = b;
        }
    }
#pragma unroll
    for (int r = 0; r < 4; ++r) {                 // 4*288 = 1152 jobs exactly
        int g2  = bid + GRID * r;
        int idb = g2 % 144;
        int bb  = g2 / 144;
        int id  = idb * 64 + (t & 63);            // (i,d) flat row
        int b0  = bb * 32 + (t >> 6) * 8;         // 8 batch elems per thread
        float v[8];
#pragma unroll
        for (int j = 0; j < 8; ++j)
            v[j] = x[(size_t)(b0 + j) * XROW + id];
        short8 h8, l8;
#pragma unroll
        for (int j = 0; j < 8; ++j) {
            unsigned short h = f2bf(v[j]);
            h8[j] = (short)h;
            l8[j] = (short)f2bf(v[j] - bf2f(h));
        }
        *(short8*)(xTh + (size_t)id * B + b0) = h8;
        *(short8*)(xTl + (size_t)id * B + b0) = l8;
    }
#pragma unroll
    for (int r = 0; r < 8; ++r) {                 // 8*288*256 float4 jobs
        int g = (bid + GRID * r) * 256 + t;
        float4 v = ((const float4*)x)[g];
        ushort4 h, l;
        h.x = f2bf(v.x); l.x = f2bf(v.x - bf2f(h.x));
        h.y = f2bf(v.y); l.y = f2bf(v.y - bf2f(h.y));
        h.z = f2bf(v.z); l.z = f2bf(v.z - bf2f(h.z));
        h.w = f2bf(v.w); l.w = f2bf(v.w - bf2f(h.w));
        ((ushort4*)xh)[g] = h;
        ((ushort4*)xl)[g] = l;
    }
    // zero s0..s2 (3 * B*OE floats) straight at the coherence point
#pragma unroll
    for (int r = 0; r < 2; ++r) {
        int idx = (bid * 256 + t) + GRID * 256 * r;
        if (idx < 3 * B * OE) AS(&sbase[idx], 0.f);
    }
}

// ---------------------------------------------------------------------------
// STAGE: spart. MFMA bf16 hi/lo split-K GEMM + routing prologue.
// it==0: c=0.1. it>=1: b=(a0[+a1])/B (plain loads), softmax -> cL.
// A fragments live in REGISTERS (xah/xal, preloaded once -- x is invariant).
// Epilogue: atomicAdd partial tile into s_it[b][oe] (device-scope, L3).
// ---------------------------------------------------------------------------
__device__ __forceinline__ void stage_spart(
    int bid, int t,
    unsigned short* __restrict__ Wh, unsigned short* __restrict__ Wl,
    float (*brow_s)[10], float (*cL)[10],
    const short8 (&xah)[2][2][2], const short8 (&xal)[2][2][2],
    const float* __restrict__ Wt,
    const float* __restrict__ a0, const float* __restrict__ a1,
    float* __restrict__ s_it, int it)
{
    int ic  = bid >> 2;
    int nb  = bid & 1;
    int mbq = (bid >> 1) & 1;
    int b0  = mbq * 128;
    int oe0 = nb * 80;
    int i0  = ic * CHUNK;

    int w    = t >> 6;
    int lane = t & 63;
    int l15  = lane & 15;
    int q    = lane >> 4;

    if (it) {
        if (t < 160) {
            int iL = t / 10;
            int o  = t - iL * 10;
            int i  = i0 + iL;
            float bo = a0[i * O + o] * (1.f / (float)B);
            if (it == 2) bo += a1[i * O + o] * (1.f / (float)B);
            brow_s[iL][o] = bo;
        }
        __syncthreads();
        if (t < 16) {
            float m = brow_s[t][0];
#pragma unroll
            for (int o = 1; o < O; ++o) m = fmaxf(m, brow_s[t][o]);
            float ex[O];
            float sum = 0.f;
#pragma unroll
            for (int o = 0; o < O; ++o) { ex[o] = __expf(brow_s[t][o] - m); sum += ex[o]; }
            float inv = 1.f / sum;
#pragma unroll
            for (int o = 0; o < O; ++o) cL[t][o] = ex[o] * inv;
        }
        __syncthreads();
    }

    floatx4 acc[2][5];
#pragma unroll
    for (int mt = 0; mt < 2; ++mt)
#pragma unroll
        for (int nt = 0; nt < 5; ++nt) acc[mt][nt] = (floatx4)(0.f);

#pragma unroll
    for (int round = 0; round < CHUNK / SI; ++round) {
        int si0 = i0 + round * SI;
        if (round) __syncthreads();

        // stage W: coalesced loads from Wt, scale by c, split hi/lo
#pragma unroll
        for (int r = 0; r < 3; ++r) {
            int p = t + 256 * r;                  // (oe-local, i-local) pair
            if (p < 640) {
                int oeL = p % 80;
                int iL  = p / 80;                 // 0..7
                int o   = (oe0 + oeL) >> 4;
                const float* wp = Wt + ((size_t)(si0 + iL) * OE + oe0 + oeL) * 8;
                float cv = it ? cL[round * SI + iL][o] : 0.1f;
                float4 w0 = *(const float4*)wp;
                float4 w1 = *(const float4*)(wp + 4);
                float wv[8] = {w0.x, w0.y, w0.z, w0.w, w1.x, w1.y, w1.z, w1.w};
                short8 hv, lv;
#pragma unroll
                for (int d = 0; d < 8; ++d) {
                    float s = wv[d] * cv;
                    unsigned short h = f2bf(s);
                    hv[d] = (short)h;
                    lv[d] = (short)f2bf(s - bf2f(h));
                }
                int off = oeL * 64 + ((iL ^ (oeL & 7)) << 3);
                *(short8*)(Wh + off) = hv;
                *(short8*)(Wl + off) = lv;
            }
        }
        __syncthreads();

        // 2 K-steps of 32 over the staged window (A from registers)
#pragma unroll
        for (int ks = 0; ks < 2; ++ks) {
#pragma unroll
            for (int nt = 0; nt < 5; ++nt) {
                int rn  = nt * 16 + l15;
                int off = rn * 64 + ((((ks << 2) + q) ^ (rn & 7)) << 3);
                short8 bh = *(const short8*)(Wh + off);
                short8 bl = *(const short8*)(Wl + off);
#pragma unroll
                for (int mt = 0; mt < 2; ++mt) {
                    acc[mt][nt] = __builtin_amdgcn_mfma_f32_16x16x32_bf16(xah[round][ks][mt], bh, acc[mt][nt], 0, 0, 0);
                    acc[mt][nt] = __builtin_amdgcn_mfma_f32_16x16x32_bf16(xah[round][ks][mt], bl, acc[mt][nt], 0, 0, 0);
                    acc[mt][nt] = __builtin_amdgcn_mfma_f32_16x16x32_bf16(xal[round][ks][mt], bh, acc[mt][nt], 0, 0, 0);
                }
            }
        }
    }

    // epilogue: atomic split-K reduction into s_it (C/D layout m89/m91)
#pragma unroll
    for (int mt = 0; mt < 2; ++mt) {
        int row0 = b0 + w * 32 + mt * 16 + q * 4;
#pragma unroll
        for (int nt = 0; nt < 5; ++nt) {
            int col = oe0 + nt * 16 + l15;
#pragma unroll
            for (int reg = 0; reg < 4; ++reg)
                atomicAdd(&s_it[(size_t)(row0 + reg) * OE + col], acc[mt][nt][reg]);
        }
    }
}

// ---------------------------------------------------------------------------
// STAGE: ggemm with fused v-computation + agree epilogue.
// Per b-window: compute v = squash(s) for [80 oe][64 b] straight from the
// reduced s (plain loads, 160 KB L2-resident), write bf16 hi/lo into the
// swizzled LDS V-buffers; then MFMA G = xT * v and reduce agree[i,o]
// in-wave against Wt. 144 of 288 blocks active. agree written sc1.
// ---------------------------------------------------------------------------
__device__ __forceinline__ void stage_ggemmv(
    int bid, int t,
    unsigned short* __restrict__ Vh, unsigned short* __restrict__ Vl,
    const unsigned short* __restrict__ xTh, const unsigned short* __restrict__ xTl,
    const float* __restrict__ s_it,
    const float* __restrict__ Wt, float* __restrict__ agree)
{
    if (bid >= 144) return;
    int m0  = (bid >> 1) * 128;
    int nb  = bid & 1;
    int oe0 = nb * 80;

    int w    = t >> 6;
    int lane = t & 63;
    int l15  = lane & 15;
    int q    = lane >> 4;

    floatx4 acc[2][5];
#pragma unroll
    for (int mt = 0; mt < 2; ++mt)
#pragma unroll
        for (int nt = 0; nt < 5; ++nt) acc[mt][nt] = (floatx4)(0.f);

#pragma unroll
    for (int win = 0; win < 4; ++win) {
        int k0 = win * 64;
        if (win) __syncthreads();

        // compute v window [80 oe][64 b] from s; 20 elems/thread.
        // p = t + 256*r: every aligned 16-lane group lies in one b-row and
        // one o-group (16 | 80), so the e-reduce is 4 shfl_xor within 16.
#pragma unroll
        for (int r = 0; r < 20; ++r) {
            int p   = t + 256 * r;                // 0..5119
            int bl  = p / 80;                     // b-local 0..63
            int oeL = p - bl * 80;                // 0..79
            float sv = s_it[(size_t)(k0 + bl) * OE + oe0 + oeL];
            float ss = sv * sv;
            ss += __shfl_xor(ss, 1, 16);
            ss += __shfl_xor(ss, 2, 16);
            ss += __shfl_xor(ss, 4, 16);
            ss += __shfl_xor(ss, 8, 16);
            float val = sv * (sqrtf(ss) / (1.f + ss));
            unsigned short h = f2bf(val);
            unsigned short lo = f2bf(val - bf2f(h));
            int ch  = bl >> 3;
            int off = oeL * 64 + ((ch ^ (oeL & 7)) << 3) + (bl & 7);
            Vh[off] = h;
            Vl[off] = lo;
        }
        __syncthreads();

        // A fragments direct from xT (read-only, L2-cached across both calls)
        short8 ah[2][2], al[2][2];
#pragma unroll
        for (int ks = 0; ks < 2; ++ks)
#pragma unroll
            for (int mt = 0; mt < 2; ++mt) {
                size_t ga = (size_t)(m0 + w * 32 + mt * 16 + l15) * B
                          + k0 + (ks << 5) + (q << 3);
                ah[ks][mt] = *(const short8*)(xTh + ga);
                al[ks][mt] = *(const short8*)(xTl + ga);
            }

#pragma unroll
        for (int ks = 0; ks < 2; ++ks) {
#pragma unroll
            for (int nt = 0; nt < 5; ++nt) {
                int rn  = nt * 16 + l15;
                int off = rn * 64 + ((((ks << 2) + q) ^ (rn & 7)) << 3);
                short8 bh = *(const short8*)(Vh + off);
                short8 bl = *(const short8*)(Vl + off);
#pragma unroll
                for (int mt = 0; mt < 2; ++mt) {
                    acc[mt][nt] = __builtin_amdgcn_mfma_f32_16x16x32_bf16(ah[ks][mt], bh, acc[mt][nt], 0, 0, 0);
                    acc[mt][nt] = __builtin_amdgcn_mfma_f32_16x16x32_bf16(ah[ks][mt], bl, acc[mt][nt], 0, 0, 0);
                    acc[mt][nt] = __builtin_amdgcn_mfma_f32_16x16x32_bf16(al[ks][mt], bh, acc[mt][nt], 0, 0, 0);
                }
            }
        }
    }

    // agree epilogue: acc[mt][nt][reg] = G[i = rb>>3][d = (rb&7)+reg][oe]
#pragma unroll
    for (int mt = 0; mt < 2; ++mt) {
        int rb = m0 + w * 32 + mt * 16 + q * 4;
        int i  = rb >> 3;
        int d0 = rb & 7;                          // 0 or 4 (q parity)
#pragma unroll
        for (int nt = 0; nt < 5; ++nt) {
            int oe = oe0 + nt * 16 + l15;
            float4 wv = *(const float4*)(Wt + (size_t)i * WROW + oe * 8 + d0);
            floatx4 a = acc[mt][nt];
            float p = a[0] * wv.x + a[1] * wv.y + a[2] * wv.z + a[3] * wv.w;
            p += __shfl_xor(p, 1);                 // e-lanes
            p += __shfl_xor(p, 2);
            p += __shfl_xor(p, 4);
            p += __shfl_xor(p, 8);
            p += __shfl_xor(p, 16);                // d-halves (q pairs)
            if ((lane & 31) == 0)
                AS(&agree[i * O + nb * 5 + nt], p);
        }
    }
}

// ---------------------------------------------------------------------------
// STAGE: out (final iteration only). Squash s2 -> output. 160 blocks.
// ---------------------------------------------------------------------------
__device__ __forceinline__ void stage_out(
    int bid, int t, const float* __restrict__ s_it, float* __restrict__ out)
{
    if (bid >= 160) return;
    int g = bid * 256 + t;                      // [b][o][e] flat
    float s = s_it[g];
    float ss = s * s;
    ss += __shfl_xor(ss, 1, 16);
    ss += __shfl_xor(ss, 2, 16);
    ss += __shfl_xor(ss, 4, 16);
    ss += __shfl_xor(ss, 8, 16);
    out[g] = s * (sqrtf(ss) / (1.f + ss));
}

// ---------------------------------------------------------------------------
// MEGA kernel: prep | spart -> ggemmv (x2) | spart -> out. 6 barriers.
// ---------------------------------------------------------------------------
__global__ __launch_bounds__(256, 2) void mega_kernel(
    const float* __restrict__ x, const float* __restrict__ W,
    float* __restrict__ out, float* __restrict__ Wt,
    unsigned short* __restrict__ xTh, unsigned short* __restrict__ xTl,
    unsigned short* __restrict__ xh,  unsigned short* __restrict__ xl,
    float* __restrict__ sbuf, float* __restrict__ a0, float* __restrict__ a1,
    unsigned* __restrict__ bar)
{
    __shared__ unsigned short Sh[80 * 64], Sl[80 * 64];   // spart & ggemm reuse
    __shared__ float brow_s[16][10];
    __shared__ float cL[16][10];

    unsigned* cnt = bar;            // cacheline 0
    unsigned* gen = bar + 32;       // cacheline 1
    int bid = blockIdx.x;
    int t   = threadIdx.x;

    // entry acquire: drop clean L2 lines left by PREVIOUS runs of this kernel
    if (t == 0) __builtin_amdgcn_fence(__ATOMIC_ACQUIRE, "agent");
    __syncthreads();

    stage_prep(bid, t, x, W, Wt, xTh, xTl, xh, xl, sbuf);
    gbar_full(cnt, gen);            // one-time: flush plain-stored prep data

    // preload spart A fragments into registers (x is iteration-invariant)
    short8 xah[2][2][2], xal[2][2][2];            // [round][ks][mt]
    {
        int ic = bid >> 2;
        int b0 = ((bid >> 1) & 1) * 128;
        int i0 = ic * CHUNK;
        int w = t >> 6, lane = t & 63, l15 = lane & 15, q = lane >> 4;
#pragma unroll
        for (int rd = 0; rd < 2; ++rd)
#pragma unroll
            for (int ks = 0; ks < 2; ++ks)
#pragma unroll
                for (int mt = 0; mt < 2; ++mt) {
                    size_t goff = (size_t)(b0 + w * 32 + mt * 16 + l15) * XROW
                                + (size_t)(i0 + rd * SI) * 8 + (ks << 5) + (q << 3);
                    xah[rd][ks][mt] = *(const short8*)(xh + goff);
                    xal[rd][ks][mt] = *(const short8*)(xl + goff);
                }
    }

    for (int it = 0; it < 3; ++it) {
        float* s_it = sbuf + (size_t)it * (B * OE);
        stage_spart(bid, t, Sh, Sl, brow_s, cL, xah, xal, Wt, a0, a1, s_it, it);
        gbar_light(cnt, gen);
        if (it < 2) {
            stage_ggemmv(bid, t, Sh, Sl, xTh, xTl, s_it, Wt, it == 0 ? a0 : a1);
            gbar_light(cnt, gen);
        } else {
            stage_out(bid, t, s_it, out);
        }
    }
}

// ---------------------------------------------------------------------------
extern "C" void kernel_launch(void* const* d_in, const int* in_sizes, int n_in,
                              void* d_out, int out_size, void* d_ws, size_t ws_size,
                              hipStream_t stream)
{
    const float* x = (const float*)d_in[0];   // [256,1152,8]
    const float* W = (const float*)d_in[1];   // [1152,10,8,16]
    float* out = (float*)d_out;               // [256,10,16,1] flat = 40960

    // ws: bar 256B | a0 | a1 | s[3] 480KB | Wt 5.9MB | xTh/xTl 9.4MB | xh/xl 9.4MB
    unsigned* bar = (unsigned*)d_ws;
    float* a0   = (float*)((char*)d_ws + 256);
    float* a1   = a0 + I * O;
    float* sbuf = a1 + I * O;
    float* Wt   = sbuf + 3 * B * OE;
    unsigned short* xTh = (unsigned short*)(Wt + (size_t)I * OE * DIN);
    unsigned short* xTl = xTh + (size_t)XROW * B;
    unsigned short* xh  = xTl + (size_t)XROW * B;
    unsigned short* xl  = xh  + (size_t)XROW * B;

    // zero barrier state (memset node is graph-capture legal)
    hipMemsetAsync(d_ws, 0, 256, stream);

    mega_kernel<<<GRID, 256, 0, stream>>>(
        x, W, out, Wt, xTh, xTl, xh, xl, sbuf, a0, a1, bar);
}

// Round 9
// 203.890 us; speedup vs baseline: 1.5292x; 1.5292x over previous
//
#include <hip/hip_runtime.h>
#include <math.h>

#define B    256
#define I    1152
#define O    10
#define DIN  8
#define DOUT 16
#define OE   160          // O*DOUT
#define XROW 9216         // I*DIN (K of the s-GEMM, M of the g-GEMM)
#define WROW 1280         // O*DIN*DOUT (= OE*DIN, Wt row length)
#define PSPLIT 36         // split-K partials (R9: halved vs R7 -> sp traffic /2)
#define CHUNK  32         // i per spart block
#define SI     8          // i per staging round (K-window 64)
#define GRID   288        // co-resident (launch_bounds(256,2): 2 blk/CU x 256 CU)

#define WPREP_JOBS 720    // I*OE/256

typedef __attribute__((ext_vector_type(8))) short short8;
typedef __attribute__((ext_vector_type(4))) float floatx4;

// sc1 store: bypass per-XCD L2, lands at the coherence point (L3).
// WRITERS of cross-stage data use AS; READERS use plain loads. Safe because
// every cross-stage buffer (sp[it], vT[it], a0/a1) has exactly ONE write
// phase before its first read within a run, writes are sc1 (no dirty L2
// copies), and the kernel-entry acquire fence invalidates clean L2 lines
// left by previous graph-replay runs (mechanism proven in R7 on a0/a1).
#define AS(p, v) __hip_atomic_store((p), (v), __ATOMIC_RELAXED, __HIP_MEMORY_SCOPE_AGENT)

__device__ __forceinline__ unsigned short f2bf(float f) {
    unsigned u = __builtin_bit_cast(unsigned, f);
    u += 0x7fffu + ((u >> 16) & 1u);          // RNE
    return (unsigned short)(u >> 16);
}
__device__ __forceinline__ float bf2f(unsigned short h) {
    unsigned u = ((unsigned)h) << 16;
    return __builtin_bit_cast(float, u);
}

// ---------------------------------------------------------------------------
// FULL barrier (one-time, after prep): flushes plain-stored prep outputs.
// ---------------------------------------------------------------------------
__device__ __forceinline__ void gbar_full(unsigned* cnt, unsigned* gen)
{
    __syncthreads();
    if (threadIdx.x == 0) {
        __builtin_amdgcn_fence(__ATOMIC_RELEASE, "agent");   // wbl2
        unsigned g = __hip_atomic_load(gen, __ATOMIC_RELAXED, __HIP_MEMORY_SCOPE_AGENT);
        unsigned a = __hip_atomic_fetch_add(cnt, 1u, __ATOMIC_RELAXED, __HIP_MEMORY_SCOPE_AGENT);
        if (a == GRID - 1u) {
            __hip_atomic_store(cnt, 0u, __ATOMIC_RELAXED, __HIP_MEMORY_SCOPE_AGENT);
            __hip_atomic_store(gen, g + 1u, __ATOMIC_RELAXED, __HIP_MEMORY_SCOPE_AGENT);
        } else {
            unsigned spins = 0;
            while (__hip_atomic_load(gen, __ATOMIC_RELAXED, __HIP_MEMORY_SCOPE_AGENT) == g) {
                __builtin_amdgcn_s_sleep(4);
                if (++spins > (1u << 20)) break;             // failsafe
            }
        }
        __builtin_amdgcn_fence(__ATOMIC_ACQUIRE, "agent");   // inv
    }
    __syncthreads();
}

// ---------------------------------------------------------------------------
// LIGHT barrier (steady state): no cache-wide fences. Writer side:
// __syncthreads() drains vmcnt(0), so all sc1 stores are at the coherence
// point before arrival. Reader side: cross-stage reads are first-touch
// plain loads of single-write-phase buffers (no stale L2 copies in-run).
// ---------------------------------------------------------------------------
__device__ __forceinline__ void gbar_light(unsigned* cnt, unsigned* gen)
{
    __syncthreads();
    if (threadIdx.x == 0) {
        unsigned g = __hip_atomic_load(gen, __ATOMIC_RELAXED, __HIP_MEMORY_SCOPE_AGENT);
        unsigned a = __hip_atomic_fetch_add(cnt, 1u, __ATOMIC_RELAXED, __HIP_MEMORY_SCOPE_AGENT);
        if (a == GRID - 1u) {
            __hip_atomic_store(cnt, 0u, __ATOMIC_RELAXED, __HIP_MEMORY_SCOPE_AGENT);
            __hip_atomic_store(gen, g + 1u, __ATOMIC_RELEASE, __HIP_MEMORY_SCOPE_AGENT);
        } else {
            unsigned spins = 0;
            while (__hip_atomic_load(gen, __ATOMIC_RELAXED, __HIP_MEMORY_SCOPE_AGENT) == g) {
                __builtin_amdgcn_s_sleep(4);
                if (++spins > (1u << 20)) break;             // failsafe
            }
        }
    }
    __syncthreads();
}

// ---------------------------------------------------------------------------
// STAGE: prep (one-time). W -> Wt[i][oe][d] fp32; x -> xTh/xTl[(i,d)][b]
// bf16 hi/lo (g-GEMM A); x -> xh/xl[b][k] bf16 hi/lo (spart A).
// ---------------------------------------------------------------------------
__device__ __forceinline__ void stage_prep(
    int bid, int t,
    const float* __restrict__ x, const float* __restrict__ W,
    float* __restrict__ Wt,
    unsigned short* __restrict__ xTh, unsigned short* __restrict__ xTl,
    unsigned short* __restrict__ xh,  unsigned short* __restrict__ xl)
{
#pragma unroll
    for (int r = 0; r < 3; ++r) {
        int job = bid + GRID * r;
        if (job < WPREP_JOBS) {
            int g  = job * 256 + t;               // (i, oe) pair
            int i  = g / OE;
            int oe = g - i * OE;
            int o  = oe >> 4;
            int e  = oe & 15;
            const float* wp = W + (size_t)i * WROW + o * (DIN * DOUT) + e;
            float4 a, b;
            a.x = wp[0 * DOUT]; a.y = wp[1 * DOUT]; a.z = wp[2 * DOUT]; a.w = wp[3 * DOUT];
            b.x = wp[4 * DOUT]; b.y = wp[5 * DOUT]; b.z = wp[6 * DOUT]; b.w = wp[7 * DOUT];
            float4* dst = (float4*)(Wt + (size_t)g * 8);
            dst[0] = a;
            dst[1] = b;
        }
    }
#pragma unroll
    for (int r = 0; r < 4; ++r) {                 // 4*288 = 1152 jobs exactly
        int g2  = bid + GRID * r;
        int idb = g2 % 144;
        int bb  = g2 / 144;
        int id  = idb * 64 + (t & 63);            // (i,d) flat row
        int b0  = bb * 32 + (t >> 6) * 8;         // 8 batch elems per thread
        float v[8];
#pragma unroll
        for (int j = 0; j < 8; ++j)
            v[j] = x[(size_t)(b0 + j) * XROW + id];
        short8 h8, l8;
#pragma unroll
        for (int j = 0; j < 8; ++j) {
            unsigned short h = f2bf(v[j]);
            h8[j] = (short)h;
            l8[j] = (short)f2bf(v[j] - bf2f(h));
        }
        *(short8*)(xTh + (size_t)id * B + b0) = h8;
        *(short8*)(xTl + (size_t)id * B + b0) = l8;
    }
#pragma unroll
    for (int r = 0; r < 8; ++r) {                 // 8*288*256 float4 jobs
        int g = (bid + GRID * r) * 256 + t;
        float4 v = ((const float4*)x)[g];
        ushort4 h, l;
        h.x = f2bf(v.x); l.x = f2bf(v.x - bf2f(h.x));
        h.y = f2bf(v.y); l.y = f2bf(v.y - bf2f(h.y));
        h.z = f2bf(v.z); l.z = f2bf(v.z - bf2f(h.z));
        h.w = f2bf(v.w); l.w = f2bf(v.w - bf2f(h.w));
        ((ushort4*)xh)[g] = h;
        ((ushort4*)xl)[g] = l;
    }
}

// ---------------------------------------------------------------------------
// STAGE: spart. MFMA bf16 hi/lo split-K GEMM + routing prologue.
// it==0: c=0.1. it>=1: b=(a0[+a1])/B (plain loads), softmax -> cL.
// CHUNK=32 (4 rounds of SI=8); 144 of 288 blocks active.
// Epilogue: sc1 stores of the partial tile into sp_it (per-iteration buffer).
// ---------------------------------------------------------------------------
__device__ __forceinline__ void stage_spart(
    int bid, int t,
    unsigned short* __restrict__ Wh, unsigned short* __restrict__ Wl,
    float (*brow_s)[10], float (*cL)[10],
    const unsigned short* __restrict__ xh, const unsigned short* __restrict__ xl,
    const float* __restrict__ Wt,
    const float* __restrict__ a0, const float* __restrict__ a1,
    float* __restrict__ sp_it, int it)
{
    int ic  = bid >> 2;                           // 0..35
    int nb  = bid & 1;
    int mbq = (bid >> 1) & 1;
    int b0  = mbq * 128;
    int oe0 = nb * 80;
    int i0  = ic * CHUNK;

    int w    = t >> 6;
    int lane = t & 63;
    int l15  = lane & 15;
    int q    = lane >> 4;

    // routing prologue: 320 (iL,o) jobs (CHUNK=32 x O=10), softmax by t<32
    if (it) {
#pragma unroll
        for (int r = 0; r < 2; ++r) {
            int p = t + 256 * r;
            if (p < 320) {
                int iL = p / 10;
                int o  = p - iL * 10;
                int i  = i0 + iL;
                float bo = a0[i * O + o] * (1.f / (float)B);
                if (it == 2) bo += a1[i * O + o] * (1.f / (float)B);
                brow_s[iL][o] = bo;
            }
        }
        __syncthreads();
        if (t < 32) {
            float m = brow_s[t][0];
#pragma unroll
            for (int o = 1; o < O; ++o) m = fmaxf(m, brow_s[t][o]);
            float ex[O];
            float sum = 0.f;
#pragma unroll
            for (int o = 0; o < O; ++o) { ex[o] = __expf(brow_s[t][o] - m); sum += ex[o]; }
            float inv = 1.f / sum;
#pragma unroll
            for (int o = 0; o < O; ++o) cL[t][o] = ex[o] * inv;
        }
        __syncthreads();
    }

    floatx4 acc[2][5];
#pragma unroll
    for (int mt = 0; mt < 2; ++mt)
#pragma unroll
        for (int nt = 0; nt < 5; ++nt) acc[mt][nt] = (floatx4)(0.f);

#pragma unroll
    for (int round = 0; round < CHUNK / SI; ++round) {
        int si0 = i0 + round * SI;
        if (round) __syncthreads();

        // X fragments: plain bf16 hi/lo loads (L2-resident across iterations
        // -- block->CU mapping is fixed for the persistent kernel)
        short8 ah[2][2], al[2][2];                // [ks][mt]
#pragma unroll
        for (int ks = 0; ks < 2; ++ks)
#pragma unroll
            for (int mt = 0; mt < 2; ++mt) {
                size_t goff = (size_t)(b0 + w * 32 + mt * 16 + l15) * XROW
                            + (size_t)si0 * 8 + (ks << 5) + (q << 3);
                ah[ks][mt] = *(const short8*)(xh + goff);
                al[ks][mt] = *(const short8*)(xl + goff);
            }

        // stage W: coalesced loads from Wt, scale by c, split hi/lo
#pragma unroll
        for (int r = 0; r < 3; ++r) {
            int p = t + 256 * r;                  // (oe-local, i-local) pair
            if (p < 640) {
                int oeL = p % 80;
                int iL  = p / 80;                 // 0..7
                int o   = (oe0 + oeL) >> 4;
                const float* wp = Wt + ((size_t)(si0 + iL) * OE + oe0 + oeL) * 8;
                float cv = it ? cL[round * SI + iL][o] : 0.1f;
                float4 w0 = *(const float4*)wp;
                float4 w1 = *(const float4*)(wp + 4);
                float wv[8] = {w0.x, w0.y, w0.z, w0.w, w1.x, w1.y, w1.z, w1.w};
                short8 hv, lv;
#pragma unroll
                for (int d = 0; d < 8; ++d) {
                    float s = wv[d] * cv;
                    unsigned short h = f2bf(s);
                    hv[d] = (short)h;
                    lv[d] = (short)f2bf(s - bf2f(h));
                }
                int off = oeL * 64 + ((iL ^ (oeL & 7)) << 3);
                *(short8*)(Wh + off) = hv;
                *(short8*)(Wl + off) = lv;
            }
        }
        __syncthreads();

        // 2 K-steps of 32 over the staged window
#pragma unroll
        for (int ks = 0; ks < 2; ++ks) {
#pragma unroll
            for (int nt = 0; nt < 5; ++nt) {
                int rn  = nt * 16 + l15;
                int off = rn * 64 + ((((ks << 2) + q) ^ (rn & 7)) << 3);
                short8 bh = *(const short8*)(Wh + off);
                short8 bl = *(const short8*)(Wl + off);
#pragma unroll
                for (int mt = 0; mt < 2; ++mt) {
                    acc[mt][nt] = __builtin_amdgcn_mfma_f32_16x16x32_bf16(ah[ks][mt], bh, acc[mt][nt], 0, 0, 0);
                    acc[mt][nt] = __builtin_amdgcn_mfma_f32_16x16x32_bf16(ah[ks][mt], bl, acc[mt][nt], 0, 0, 0);
                    acc[mt][nt] = __builtin_amdgcn_mfma_f32_16x16x32_bf16(al[ks][mt], bh, acc[mt][nt], 0, 0, 0);
                }
            }
        }
    }

    // epilogue: sc1 stores of the partial tile (C/D layout m89/m91)
    float* base = sp_it + (size_t)ic * (B * OE);
#pragma unroll
    for (int mt = 0; mt < 2; ++mt) {
        int row0 = b0 + w * 32 + mt * 16 + q * 4;
#pragma unroll
        for (int nt = 0; nt < 5; ++nt) {
            int col = oe0 + nt * 16 + l15;
#pragma unroll
            for (int reg = 0; reg < 4; ++reg)
                AS(&base[(row0 + reg) * OE + col], acc[mt][nt][reg]);
        }
    }
}

// ---------------------------------------------------------------------------
// STAGE: vred. Sum PSPLIT partials (plain float4 loads, first-touch) +
// squash; iters 0,1 -> packed v bf16 hi|lo [oe][b] (sc1); iter 2 -> out.
// 40 of 288 blocks active (10240 float4 jobs).
// ---------------------------------------------------------------------------
__device__ __forceinline__ void stage_vred(
    int bid, int t, const float* __restrict__ sp_it, float* __restrict__ out,
    unsigned* __restrict__ vT, int last)
{
    if (bid >= 40) return;
    int qd = bid * 256 + t;                     // float4 index over [b][o][e]
    float4 s = {0.f, 0.f, 0.f, 0.f};
#pragma unroll
    for (int ic = 0; ic < PSPLIT; ++ic) {
        float4 p = ((const float4*)(sp_it + (size_t)ic * (B * OE)))[qd];
        s.x += p.x; s.y += p.y; s.z += p.z; s.w += p.w;
    }
    // squash over e=16: 4 elems/lane, 4 lanes per (b,o) group (aligned)
    float ss = s.x * s.x + s.y * s.y + s.z * s.z + s.w * s.w;
    ss += __shfl_xor(ss, 1);
    ss += __shfl_xor(ss, 2);
    float f = sqrtf(ss) / (1.f + ss);
    float4 val = {s.x * f, s.y * f, s.z * f, s.w * f};

    if (last) {
        ((float4*)out)[qd] = val;
    } else {
        int e0 = qd * 4;
        int b  = e0 / OE;
        int oe = e0 - b * OE;
        float vv[4] = {val.x, val.y, val.z, val.w};
#pragma unroll
        for (int j = 0; j < 4; ++j) {
            unsigned short h = f2bf(vv[j]);
            unsigned pack = (unsigned)h | ((unsigned)f2bf(vv[j] - bf2f(h)) << 16);
            AS(&vT[(oe + j) * B + b], pack);
        }
    }
}

// ---------------------------------------------------------------------------
// STAGE: ggemm + in-wave agree epilogue. G[(i,d)][oe] = sum_b xT*v via MFMA;
// v staged from packed vT via PLAIN uint4 loads (L2-cached; ~one L3 fetch
// per XCD instead of 144x sc1 redundancy). agree written sc1.
// 144 of 288 blocks active.
// ---------------------------------------------------------------------------
__device__ __forceinline__ void stage_ggemm(
    int bid, int t,
    unsigned short* __restrict__ Vh, unsigned short* __restrict__ Vl,
    const unsigned short* __restrict__ xTh, const unsigned short* __restrict__ xTl,
    const unsigned* __restrict__ vT,
    const float* __restrict__ Wt, float* __restrict__ agree)
{
    if (bid >= 144) return;
    int m0  = (bid >> 1) * 128;
    int nb  = bid & 1;
    int oe0 = nb * 80;

    int w    = t >> 6;
    int lane = t & 63;
    int l15  = lane & 15;
    int q    = lane >> 4;

    floatx4 acc[2][5];
#pragma unroll
    for (int mt = 0; mt < 2; ++mt)
#pragma unroll
        for (int nt = 0; nt < 5; ++nt) acc[mt][nt] = (floatx4)(0.f);

#pragma unroll
    for (int win = 0; win < 4; ++win) {
        int k0 = win * 64;
        if (win) __syncthreads();

        // stage V window [80 oe][64 b] from packed vT, XOR-swizzled short8
#pragma unroll
        for (int r = 0; r < 3; ++r) {
            int p = t + 256 * r;
            if (p < 640) {
                int row = p >> 3;
                int ch  = p & 7;
                const unsigned* vp = vT + (size_t)(oe0 + row) * B + k0 + (ch << 3);
                uint4 u0 = *(const uint4*)vp;
                uint4 u1 = *(const uint4*)(vp + 4);
                unsigned uu[8] = {u0.x, u0.y, u0.z, u0.w, u1.x, u1.y, u1.z, u1.w};
                short8 hv, lv;
#pragma unroll
                for (int j = 0; j < 8; ++j) {
                    hv[j] = (short)(uu[j] & 0xffffu);
                    lv[j] = (short)(uu[j] >> 16);
                }
                int off = row * 64 + ((ch ^ (row & 7)) << 3);
                *(short8*)(Vh + off) = hv;
                *(short8*)(Vl + off) = lv;
            }
        }
        __syncthreads();

        // A fragments direct from xT (read-only, L2-cached)
        short8 ah[2][2], al[2][2];
#pragma unroll
        for (int ks = 0; ks < 2; ++ks)
#pragma unroll
            for (int mt = 0; mt < 2; ++mt) {
                size_t ga = (size_t)(m0 + w * 32 + mt * 16 + l15) * B
                          + k0 + (ks << 5) + (q << 3);
                ah[ks][mt] = *(const short8*)(xTh + ga);
                al[ks][mt] = *(const short8*)(xTl + ga);
            }

#pragma unroll
        for (int ks = 0; ks < 2; ++ks) {
#pragma unroll
            for (int nt = 0; nt < 5; ++nt) {
                int rn  = nt * 16 + l15;
                int off = rn * 64 + ((((ks << 2) + q) ^ (rn & 7)) << 3);
                short8 bh = *(const short8*)(Vh + off);
                short8 bl = *(const short8*)(Vl + off);
#pragma unroll
                for (int mt = 0; mt < 2; ++mt) {
                    acc[mt][nt] = __builtin_amdgcn_mfma_f32_16x16x32_bf16(ah[ks][mt], bh, acc[mt][nt], 0, 0, 0);
                    acc[mt][nt] = __builtin_amdgcn_mfma_f32_16x16x32_bf16(ah[ks][mt], bl, acc[mt][nt], 0, 0, 0);
                    acc[mt][nt] = __builtin_amdgcn_mfma_f32_16x16x32_bf16(al[ks][mt], bh, acc[mt][nt], 0, 0, 0);
                }
            }
        }
    }

    // agree epilogue: acc[mt][nt][reg] = G[i = rb>>3][d = (rb&7)+reg][oe]
#pragma unroll
    for (int mt = 0; mt < 2; ++mt) {
        int rb = m0 + w * 32 + mt * 16 + q * 4;
        int i  = rb >> 3;
        int d0 = rb & 7;                          // 0 or 4 (q parity)
#pragma unroll
        for (int nt = 0; nt < 5; ++nt) {
            int oe = oe0 + nt * 16 + l15;
            float4 wv = *(const float4*)(Wt + (size_t)i * WROW + oe * 8 + d0);
            floatx4 a = acc[mt][nt];
            float p = a[0] * wv.x + a[1] * wv.y + a[2] * wv.z + a[3] * wv.w;
            p += __shfl_xor(p, 1);                 // e-lanes
            p += __shfl_xor(p, 2);
            p += __shfl_xor(p, 4);
            p += __shfl_xor(p, 8);
            p += __shfl_xor(p, 16);                // d-halves (q pairs)
            if ((lane & 31) == 0)
                AS(&agree[i * O + nb * 5 + nt], p);
        }
    }
}

// ---------------------------------------------------------------------------
// MEGA kernel: prep | [spart | vred | ggemm] x2 | spart | vred->out.
// 1 full + 7 light barriers.
// ---------------------------------------------------------------------------
__global__ __launch_bounds__(256, 2) void mega_kernel(
    const float* __restrict__ x, const float* __restrict__ W,
    float* __restrict__ out, float* __restrict__ Wt,
    unsigned short* __restrict__ xTh, unsigned short* __restrict__ xTl,
    unsigned short* __restrict__ xh,  unsigned short* __restrict__ xl,
    unsigned* __restrict__ vT0, unsigned* __restrict__ vT1,
    float* __restrict__ sbuf, float* __restrict__ a0, float* __restrict__ a1,
    unsigned* __restrict__ bar)
{
    __shared__ unsigned short Sh[80 * 64], Sl[80 * 64];   // spart & ggemm reuse
    __shared__ float brow_s[32][10];
    __shared__ float cL[32][10];

    unsigned* cnt = bar;            // cacheline 0
    unsigned* gen = bar + 32;       // cacheline 1
    int bid = blockIdx.x;
    int t   = threadIdx.x;

    // entry acquire: drop clean L2 lines left by PREVIOUS runs of this kernel
    if (t == 0) __builtin_amdgcn_fence(__ATOMIC_ACQUIRE, "agent");
    __syncthreads();

    stage_prep(bid, t, x, W, Wt, xTh, xTl, xh, xl);
    gbar_full(cnt, gen);            // one-time: flush plain-stored prep data

    for (int it = 0; it < 3; ++it) {
        float* sp_it = sbuf + (size_t)it * PSPLIT * (B * OE);
        unsigned* vT = (it == 0) ? vT0 : vT1;
        if (bid < 4 * PSPLIT)
            stage_spart(bid, t, Sh, Sl, brow_s, cL, xh, xl, Wt, a0, a1, sp_it, it);
        gbar_light(cnt, gen);
        stage_vred(bid, t, sp_it, out, vT, it == 2);
        if (it == 2) break;
        gbar_light(cnt, gen);
        stage_ggemm(bid, t, Sh, Sl, xTh, xTl, vT, Wt, it == 0 ? a0 : a1);
        gbar_light(cnt, gen);
    }
}

// ---------------------------------------------------------------------------
extern "C" void kernel_launch(void* const* d_in, const int* in_sizes, int n_in,
                              void* d_out, int out_size, void* d_ws, size_t ws_size,
                              hipStream_t stream)
{
    const float* x = (const float*)d_in[0];   // [256,1152,8]
    const float* W = (const float*)d_in[1];   // [1152,10,8,16]
    float* out = (float*)d_out;               // [256,10,16,1] flat = 40960

    // ws: bar 256B | a0 | a1 | Wt 5.9MB | sp[3] 17.7MB | xTh/xTl 9.4MB |
    //     xh/xl 9.4MB | vT0/vT1 320KB     (~43 MB of 256 MB)
    unsigned* bar = (unsigned*)d_ws;
    float* a0   = (float*)((char*)d_ws + 256);
    float* a1   = a0 + I * O;
    float* Wt   = a1 + I * O;
    float* sbuf = Wt + (size_t)I * OE * DIN;
    unsigned short* xTh = (unsigned short*)(sbuf + (size_t)3 * PSPLIT * B * OE);
    unsigned short* xTl = xTh + (size_t)XROW * B;
    unsigned short* xh  = xTl + (size_t)XROW * B;
    unsigned short* xl  = xh  + (size_t)XROW * B;
    unsigned* vT0       = (unsigned*)(xl + (size_t)XROW * B);
    unsigned* vT1       = vT0 + B * OE;

    // zero barrier state (memset node is graph-capture legal)
    hipMemsetAsync(d_ws, 0, 256, stream);

    mega_kernel<<<GRID, 256, 0, stream>>>(
        x, W, out, Wt, xTh, xTl, xh, xl, vT0, vT1, sbuf, a0, a1, bar);
}

// Round 10
// 170.008 us; speedup vs baseline: 1.8340x; 1.1993x over previous
//
#include <hip/hip_runtime.h>
#include <math.h>

#define B    256
#define I    1152
#define O    10
#define DIN  8
#define DOUT 16
#define OE   160          // O*DOUT
#define XROW 9216         // I*DIN (K of the s-GEMM, M of the g-GEMM)
#define WROW 1280         // O*DIN*DOUT (= OE*DIN, Wt row length)
#define IO   11520        // I*O
#define PSPLIT 36         // split-K partials (sp round-trip halved vs R7)
#define CHUNK  32         // i per spart block
#define SI     8          // i per staging round (K-window 64)
#define GRID   288        // co-resident (launch_bounds(256,2))

#define WPREP_JOBS 720    // I*OE/256

typedef __attribute__((ext_vector_type(8))) short short8;
typedef __attribute__((ext_vector_type(4))) float floatx4;

// sc1 store: bypass per-XCD L2, lands at the coherence point (L3).
// WRITERS of cross-stage data use AS; READERS use plain loads (each buffer
// has ONE write phase before first read in-run; entry acquire fence drops
// stale lines from previous graph replays -- mechanism proven R7).
#define AS(p, v) __hip_atomic_store((p), (v), __ATOMIC_RELAXED, __HIP_MEMORY_SCOPE_AGENT)

__device__ __forceinline__ unsigned short f2bf(float f) {
    unsigned u = __builtin_bit_cast(unsigned, f);
    u += 0x7fffu + ((u >> 16) & 1u);          // RNE
    return (unsigned short)(u >> 16);
}
__device__ __forceinline__ float bf2f(unsigned short h) {
    unsigned u = ((unsigned)h) << 16;
    return __builtin_bit_cast(float, u);
}

// ---------------------------------------------------------------------------
// FULL barrier (one-time, after prep): flushes plain-stored prep outputs.
// ---------------------------------------------------------------------------
__device__ __forceinline__ void gbar_full(unsigned* cnt, unsigned* gen)
{
    __syncthreads();
    if (threadIdx.x == 0) {
        __builtin_amdgcn_fence(__ATOMIC_RELEASE, "agent");   // wbl2
        unsigned g = __hip_atomic_load(gen, __ATOMIC_RELAXED, __HIP_MEMORY_SCOPE_AGENT);
        unsigned a = __hip_atomic_fetch_add(cnt, 1u, __ATOMIC_RELAXED, __HIP_MEMORY_SCOPE_AGENT);
        if (a == GRID - 1u) {
            __hip_atomic_store(cnt, 0u, __ATOMIC_RELAXED, __HIP_MEMORY_SCOPE_AGENT);
            __hip_atomic_store(gen, g + 1u, __ATOMIC_RELAXED, __HIP_MEMORY_SCOPE_AGENT);
        } else {
            unsigned spins = 0;
            while (__hip_atomic_load(gen, __ATOMIC_RELAXED, __HIP_MEMORY_SCOPE_AGENT) == g) {
                __builtin_amdgcn_s_sleep(1);
                if (++spins > (1u << 21)) break;             // failsafe
            }
        }
        __builtin_amdgcn_fence(__ATOMIC_ACQUIRE, "agent");   // inv
    }
    __syncthreads();
}

// ---------------------------------------------------------------------------
// LIGHT barrier (steady state): no cache-wide fences (rationale as R7).
// ---------------------------------------------------------------------------
__device__ __forceinline__ void gbar_light(unsigned* cnt, unsigned* gen)
{
    __syncthreads();
    if (threadIdx.x == 0) {
        unsigned g = __hip_atomic_load(gen, __ATOMIC_RELAXED, __HIP_MEMORY_SCOPE_AGENT);
        unsigned a = __hip_atomic_fetch_add(cnt, 1u, __ATOMIC_RELAXED, __HIP_MEMORY_SCOPE_AGENT);
        if (a == GRID - 1u) {
            __hip_atomic_store(cnt, 0u, __ATOMIC_RELAXED, __HIP_MEMORY_SCOPE_AGENT);
            __hip_atomic_store(gen, g + 1u, __ATOMIC_RELEASE, __HIP_MEMORY_SCOPE_AGENT);
        } else {
            unsigned spins = 0;
            while (__hip_atomic_load(gen, __ATOMIC_RELAXED, __HIP_MEMORY_SCOPE_AGENT) == g) {
                __builtin_amdgcn_s_sleep(1);
                if (++spins > (1u << 21)) break;             // failsafe
            }
        }
    }
    __syncthreads();
}

// ---------------------------------------------------------------------------
// STAGE: prep (one-time). W -> Wt[i][oe][d] fp32; x -> xTh/xTl[(i,d)][b]
// bf16 hi/lo (g-GEMM A); x -> xh/xl[b][k] bf16 hi/lo (spart A).
// ---------------------------------------------------------------------------
__device__ __forceinline__ void stage_prep(
    int bid, int t,
    const float* __restrict__ x, const float* __restrict__ W,
    float* __restrict__ Wt,
    unsigned short* __restrict__ xTh, unsigned short* __restrict__ xTl,
    unsigned short* __restrict__ xh,  unsigned short* __restrict__ xl)
{
#pragma unroll
    for (int r = 0; r < 3; ++r) {
        int job = bid + GRID * r;
        if (job < WPREP_JOBS) {
            int g  = job * 256 + t;               // (i, oe) pair
            int i  = g / OE;
            int oe = g - i * OE;
            int o  = oe >> 4;
            int e  = oe & 15;
            const float* wp = W + (size_t)i * WROW + o * (DIN * DOUT) + e;
            float4 a, b;
            a.x = wp[0 * DOUT]; a.y = wp[1 * DOUT]; a.z = wp[2 * DOUT]; a.w = wp[3 * DOUT];
            b.x = wp[4 * DOUT]; b.y = wp[5 * DOUT]; b.z = wp[6 * DOUT]; b.w = wp[7 * DOUT];
            float4* dst = (float4*)(Wt + (size_t)g * 8);
            dst[0] = a;
            dst[1] = b;
        }
    }
#pragma unroll
    for (int r = 0; r < 4; ++r) {                 // 4*288 = 1152 jobs exactly
        int g2  = bid + GRID * r;
        int idb = g2 % 144;
        int bb  = g2 / 144;
        int id  = idb * 64 + (t & 63);            // (i,d) flat row
        int b0  = bb * 32 + (t >> 6) * 8;         // 8 batch elems per thread
        float v[8];
#pragma unroll
        for (int j = 0; j < 8; ++j)
            v[j] = x[(size_t)(b0 + j) * XROW + id];
        short8 h8, l8;
#pragma unroll
        for (int j = 0; j < 8; ++j) {
            unsigned short h = f2bf(v[j]);
            h8[j] = (short)h;
            l8[j] = (short)f2bf(v[j] - bf2f(h));
        }
        *(short8*)(xTh + (size_t)id * B + b0) = h8;
        *(short8*)(xTl + (size_t)id * B + b0) = l8;
    }
#pragma unroll
    for (int r = 0; r < 8; ++r) {                 // 8*288*256 float4 jobs
        int g = (bid + GRID * r) * 256 + t;
        float4 v = ((const float4*)x)[g];
        ushort4 h, l;
        h.x = f2bf(v.x); l.x = f2bf(v.x - bf2f(h.x));
        h.y = f2bf(v.y); l.y = f2bf(v.y - bf2f(h.y));
        h.z = f2bf(v.z); l.z = f2bf(v.z - bf2f(h.z));
        h.w = f2bf(v.w); l.w = f2bf(v.w - bf2f(h.w));
        ((ushort4*)xh)[g] = h;
        ((ushort4*)xl)[g] = l;
    }
}

// ---------------------------------------------------------------------------
// STAGE: spart. MFMA bf16 hi/lo split-K GEMM + routing prologue.
// R10: 8-way block split per K-chunk -- ic=bid>>3 (36 chunks), mb=(bid>>1)&3
// (64-row slab), nb=bid&1 (80 cols). ALL 288 blocks active (R9 had 144).
// Wave tile 16x80 (acc[5], 20 VGPR). CHUNK=32, 4 rounds of SI=8.
// it==0: c=0.1. it>=1: b = sum of two kb agree slices (plain loads), softmax.
// Epilogue: sc1 stores of the partial tile into sp_it.
// ---------------------------------------------------------------------------
__device__ __forceinline__ void stage_spart(
    int bid, int t,
    unsigned short* __restrict__ Wh, unsigned short* __restrict__ Wl,
    float (*brow_s)[10], float (*cL)[10],
    const unsigned short* __restrict__ xh, const unsigned short* __restrict__ xl,
    const float* __restrict__ Wt,
    const float* __restrict__ a0, const float* __restrict__ a1,
    float* __restrict__ sp_it, int it)
{
    int ic  = bid >> 3;                           // 0..35
    int mb  = (bid >> 1) & 3;                     // 0..3
    int nb  = bid & 1;
    int b0  = mb * 64;
    int oe0 = nb * 80;
    int i0  = ic * CHUNK;

    int w    = t >> 6;
    int lane = t & 63;
    int l15  = lane & 15;
    int q    = lane >> 4;

    // routing prologue: 320 (iL,o) jobs; logits = sum of kb slices / B
    if (it) {
#pragma unroll
        for (int r = 0; r < 2; ++r) {
            int p = t + 256 * r;
            if (p < 320) {
                int iL = p / 10;
                int o  = p - iL * 10;
                int i  = i0 + iL;
                float bo = (a0[i * O + o] + a0[IO + i * O + o]) * (1.f / (float)B);
                if (it == 2)
                    bo += (a1[i * O + o] + a1[IO + i * O + o]) * (1.f / (float)B);
                brow_s[iL][o] = bo;
            }
        }
        __syncthreads();
        if (t < 32) {
            float m = brow_s[t][0];
#pragma unroll
            for (int o = 1; o < O; ++o) m = fmaxf(m, brow_s[t][o]);
            float ex[O];
            float sum = 0.f;
#pragma unroll
            for (int o = 0; o < O; ++o) { ex[o] = __expf(brow_s[t][o] - m); sum += ex[o]; }
            float inv = 1.f / sum;
#pragma unroll
            for (int o = 0; o < O; ++o) cL[t][o] = ex[o] * inv;
        }
        __syncthreads();
    }

    floatx4 acc[5];
#pragma unroll
    for (int nt = 0; nt < 5; ++nt) acc[nt] = (floatx4)(0.f);

#pragma unroll
    for (int round = 0; round < CHUNK / SI; ++round) {
        int si0 = i0 + round * SI;
        if (round) __syncthreads();

        // X fragments: plain bf16 hi/lo loads (L2-cached, iteration-invariant)
        short8 ah[2], al[2];                      // [ks]
#pragma unroll
        for (int ks = 0; ks < 2; ++ks) {
            size_t goff = (size_t)(b0 + w * 16 + l15) * XROW
                        + (size_t)si0 * 8 + (ks << 5) + (q << 3);
            ah[ks] = *(const short8*)(xh + goff);
            al[ks] = *(const short8*)(xl + goff);
        }

        // stage W: coalesced loads from Wt, scale by c, split hi/lo
        // (redundant across the 4 mb slabs -- L2-cacheable, accepted)
#pragma unroll
        for (int r = 0; r < 3; ++r) {
            int p = t + 256 * r;                  // (oe-local, i-local) pair
            if (p < 640) {
                int oeL = p % 80;
                int iL  = p / 80;                 // 0..7
                int o   = (oe0 + oeL) >> 4;
                const float* wp = Wt + ((size_t)(si0 + iL) * OE + oe0 + oeL) * 8;
                float cv = it ? cL[round * SI + iL][o] : 0.1f;
                float4 w0 = *(const float4*)wp;
                float4 w1 = *(const float4*)(wp + 4);
                float wv[8] = {w0.x, w0.y, w0.z, w0.w, w1.x, w1.y, w1.z, w1.w};
                short8 hv, lv;
#pragma unroll
                for (int d = 0; d < 8; ++d) {
                    float s = wv[d] * cv;
                    unsigned short h = f2bf(s);
                    hv[d] = (short)h;
                    lv[d] = (short)f2bf(s - bf2f(h));
                }
                int off = oeL * 64 + ((iL ^ (oeL & 7)) << 3);
                *(short8*)(Wh + off) = hv;
                *(short8*)(Wl + off) = lv;
            }
        }
        __syncthreads();

        // 2 K-steps of 32 over the staged window
#pragma unroll
        for (int ks = 0; ks < 2; ++ks) {
#pragma unroll
            for (int nt = 0; nt < 5; ++nt) {
                int rn  = nt * 16 + l15;
                int off = rn * 64 + ((((ks << 2) + q) ^ (rn & 7)) << 3);
                short8 bh = *(const short8*)(Wh + off);
                short8 bl = *(const short8*)(Wl + off);
                acc[nt] = __builtin_amdgcn_mfma_f32_16x16x32_bf16(ah[ks], bh, acc[nt], 0, 0, 0);
                acc[nt] = __builtin_amdgcn_mfma_f32_16x16x32_bf16(ah[ks], bl, acc[nt], 0, 0, 0);
                acc[nt] = __builtin_amdgcn_mfma_f32_16x16x32_bf16(al[ks], bh, acc[nt], 0, 0, 0);
            }
        }
    }

    // epilogue: sc1 stores of the partial tile (C/D layout m89/m91)
    float* base = sp_it + (size_t)ic * (B * OE);
    int row0 = b0 + w * 16 + q * 4;
#pragma unroll
    for (int nt = 0; nt < 5; ++nt) {
        int col = oe0 + nt * 16 + l15;
#pragma unroll
        for (int reg = 0; reg < 4; ++reg)
            AS(&base[(size_t)(row0 + reg) * OE + col], acc[nt][reg]);
    }
}

// ---------------------------------------------------------------------------
// STAGE: vred. Sum PSPLIT partials (plain scalar loads, coalesced, first-
// touch) + squash; iters 0,1 -> packed v bf16 hi|lo [oe][b] (sc1 store);
// iter 2 -> final out. 160 of 288 blocks active (R7-proven shape).
// ---------------------------------------------------------------------------
__device__ __forceinline__ void stage_vred(
    int bid, int t, const float* __restrict__ sp_it, float* __restrict__ out,
    unsigned* __restrict__ vT, int last)
{
    if (bid >= 160) return;
    int g = bid * 256 + t;                      // [b][o][e] flat
    float s = 0.f;
#pragma unroll 6
    for (int ic = 0; ic < PSPLIT; ++ic) s += sp_it[(size_t)ic * (B * OE) + g];

    float ss = s * s;
    ss += __shfl_xor(ss, 1, 16);
    ss += __shfl_xor(ss, 2, 16);
    ss += __shfl_xor(ss, 4, 16);
    ss += __shfl_xor(ss, 8, 16);
    float f = sqrtf(ss) / (1.f + ss);           // squash factor
    float val = s * f;

    if (last) {
        out[g] = val;
    } else {
        int b  = g / OE;
        int oe = g - b * OE;
        unsigned short h = f2bf(val);
        unsigned pack = (unsigned)h | ((unsigned)f2bf(val - bf2f(h)) << 16);
        AS(&vT[oe * B + b], pack);
    }
}

// ---------------------------------------------------------------------------
// STAGE: ggemm + in-wave agree epilogue. R10: kb x 2 split over the b (=K)
// dimension -> ALL 288 blocks active (was 144), each does 2 of 4 b-windows.
// Per-kb agree slice written without atomics (summed in spart prologue).
// v staged from packed vT via PLAIN uint4 loads (L2-reusable).
// ---------------------------------------------------------------------------
__device__ __forceinline__ void stage_ggemm(
    int bid, int t,
    unsigned short* __restrict__ Vh, unsigned short* __restrict__ Vl,
    const unsigned short* __restrict__ xTh, const unsigned short* __restrict__ xTl,
    const unsigned* __restrict__ vT,
    const float* __restrict__ Wt, float* __restrict__ agreeP)
{
    int m0  = (bid >> 2) * 128;                   // 0..71 m-blocks
    int nb  = (bid >> 1) & 1;
    int kb  = bid & 1;
    int oe0 = nb * 80;

    int w    = t >> 6;
    int lane = t & 63;
    int l15  = lane & 15;
    int q    = lane >> 4;

    floatx4 acc[2][5];
#pragma unroll
    for (int mt = 0; mt < 2; ++mt)
#pragma unroll
        for (int nt = 0; nt < 5; ++nt) acc[mt][nt] = (floatx4)(0.f);

#pragma unroll
    for (int win = 0; win < 2; ++win) {
        int k0 = kb * 128 + win * 64;
        if (win) __syncthreads();

        // stage V window [80 oe][64 b] from packed vT, XOR-swizzled short8
#pragma unroll
        for (int r = 0; r < 3; ++r) {
            int p = t + 256 * r;
            if (p < 640) {
                int row = p >> 3;
                int ch  = p & 7;
                const unsigned* vp = vT + (size_t)(oe0 + row) * B + k0 + (ch << 3);
                uint4 u0 = *(const uint4*)vp;
                uint4 u1 = *(const uint4*)(vp + 4);
                unsigned uu[8] = {u0.x, u0.y, u0.z, u0.w, u1.x, u1.y, u1.z, u1.w};
                short8 hv, lv;
#pragma unroll
                for (int j = 0; j < 8; ++j) {
                    hv[j] = (short)(uu[j] & 0xffffu);
                    lv[j] = (short)(uu[j] >> 16);
                }
                int off = row * 64 + ((ch ^ (row & 7)) << 3);
                *(short8*)(Vh + off) = hv;
                *(short8*)(Vl + off) = lv;
            }
        }
        __syncthreads();

        // A fragments direct from xT (read-only, L2-cached)
        short8 ah[2][2], al[2][2];
#pragma unroll
        for (int ks = 0; ks < 2; ++ks)
#pragma unroll
            for (int mt = 0; mt < 2; ++mt) {
                size_t ga = (size_t)(m0 + w * 32 + mt * 16 + l15) * B
                          + k0 + (ks << 5) + (q << 3);
                ah[ks][mt] = *(const short8*)(xTh + ga);
                al[ks][mt] = *(const short8*)(xTl + ga);
            }

#pragma unroll
        for (int ks = 0; ks < 2; ++ks) {
#pragma unroll
            for (int nt = 0; nt < 5; ++nt) {
                int rn  = nt * 16 + l15;
                int off = rn * 64 + ((((ks << 2) + q) ^ (rn & 7)) << 3);
                short8 bh = *(const short8*)(Vh + off);
                short8 bl = *(const short8*)(Vl + off);
#pragma unroll
                for (int mt = 0; mt < 2; ++mt) {
                    acc[mt][nt] = __builtin_amdgcn_mfma_f32_16x16x32_bf16(ah[ks][mt], bh, acc[mt][nt], 0, 0, 0);
                    acc[mt][nt] = __builtin_amdgcn_mfma_f32_16x16x32_bf16(ah[ks][mt], bl, acc[mt][nt], 0, 0, 0);
                    acc[mt][nt] = __builtin_amdgcn_mfma_f32_16x16x32_bf16(al[ks][mt], bh, acc[mt][nt], 0, 0, 0);
                }
            }
        }
    }

    // agree epilogue into this block's kb slice (no atomics)
    float* aP = agreeP + (size_t)kb * IO;
#pragma unroll
    for (int mt = 0; mt < 2; ++mt) {
        int rb = m0 + w * 32 + mt * 16 + q * 4;
        int i  = rb >> 3;
        int d0 = rb & 7;                          // 0 or 4 (q parity)
#pragma unroll
        for (int nt = 0; nt < 5; ++nt) {
            int oe = oe0 + nt * 16 + l15;
            float4 wv = *(const float4*)(Wt + (size_t)i * WROW + oe * 8 + d0);
            floatx4 a = acc[mt][nt];
            float p = a[0] * wv.x + a[1] * wv.y + a[2] * wv.z + a[3] * wv.w;
            p += __shfl_xor(p, 1);                 // e-lanes
            p += __shfl_xor(p, 2);
            p += __shfl_xor(p, 4);
            p += __shfl_xor(p, 8);
            p += __shfl_xor(p, 16);                // d-halves (q pairs)
            if ((lane & 31) == 0)
                AS(&aP[i * O + nb * 5 + nt], p);
        }
    }
}

// ---------------------------------------------------------------------------
// MEGA kernel: prep | [spart | vred | ggemm] x2 | spart | vred->out.
// 1 full + 7 light barriers. All heavy stages run 288 blocks wide.
// ---------------------------------------------------------------------------
__global__ __launch_bounds__(256, 2) void mega_kernel(
    const float* __restrict__ x, const float* __restrict__ W,
    float* __restrict__ out, float* __restrict__ Wt,
    unsigned short* __restrict__ xTh, unsigned short* __restrict__ xTl,
    unsigned short* __restrict__ xh,  unsigned short* __restrict__ xl,
    unsigned* __restrict__ vT0, unsigned* __restrict__ vT1,
    float* __restrict__ sbuf, float* __restrict__ a0, float* __restrict__ a1,
    unsigned* __restrict__ bar)
{
    __shared__ unsigned short Sh[80 * 64], Sl[80 * 64];   // spart & ggemm reuse
    __shared__ float brow_s[32][10];
    __shared__ float cL[32][10];

    unsigned* cnt = bar;            // cacheline 0
    unsigned* gen = bar + 32;       // cacheline 1
    int bid = blockIdx.x;
    int t   = threadIdx.x;

    // entry acquire: drop clean L2 lines left by PREVIOUS runs of this kernel
    if (t == 0) __builtin_amdgcn_fence(__ATOMIC_ACQUIRE, "agent");
    __syncthreads();

    stage_prep(bid, t, x, W, Wt, xTh, xTl, xh, xl);
    gbar_full(cnt, gen);            // one-time: flush plain-stored prep data

    for (int it = 0; it < 3; ++it) {
        float* sp_it = sbuf + (size_t)it * PSPLIT * (B * OE);
        unsigned* vT = (it == 0) ? vT0 : vT1;
        stage_spart(bid, t, Sh, Sl, brow_s, cL, xh, xl, Wt, a0, a1, sp_it, it);
        gbar_light(cnt, gen);
        stage_vred(bid, t, sp_it, out, vT, it == 2);
        if (it == 2) break;
        gbar_light(cnt, gen);
        stage_ggemm(bid, t, Sh, Sl, xTh, xTl, vT, Wt, it == 0 ? a0 : a1);
        gbar_light(cnt, gen);
    }
}

// ---------------------------------------------------------------------------
extern "C" void kernel_launch(void* const* d_in, const int* in_sizes, int n_in,
                              void* d_out, int out_size, void* d_ws, size_t ws_size,
                              hipStream_t stream)
{
    const float* x = (const float*)d_in[0];   // [256,1152,8]
    const float* W = (const float*)d_in[1];   // [1152,10,8,16]
    float* out = (float*)d_out;               // [256,10,16,1] flat = 40960

    // ws: bar 256B | a0 2*IO | a1 2*IO | Wt 5.9MB | sp[3] 17.7MB |
    //     xTh/xTl 9.4MB | xh/xl 9.4MB | vT0/vT1 320KB   (~43 MB of 256 MB)
    unsigned* bar = (unsigned*)d_ws;
    float* a0   = (float*)((char*)d_ws + 256);
    float* a1   = a0 + 2 * IO;
    float* Wt   = a1 + 2 * IO;
    float* sbuf = Wt + (size_t)I * OE * DIN;
    unsigned short* xTh = (unsigned short*)(sbuf + (size_t)3 * PSPLIT * B * OE);
    unsigned short* xTl = xTh + (size_t)XROW * B;
    unsigned short* xh  = xTl + (size_t)XROW * B;
    unsigned short* xl  = xh  + (size_t)XROW * B;
    unsigned* vT0       = (unsigned*)(xl + (size_t)XROW * B);
    unsigned* vT1       = vT0 + B * OE;

    // zero barrier state (memset node is graph-capture legal)
    hipMemsetAsync(d_ws, 0, 256, stream);

    mega_kernel<<<GRID, 256, 0, stream>>>(
        x, W, out, Wt, xTh, xTl, xh, xl, vT0, vT1, sbuf, a0, a1, bar);
}

// Round 11
// 167.584 us; speedup vs baseline: 1.8605x; 1.0145x over previous
//
#include <hip/hip_runtime.h>
#include <math.h>

#define B    256
#define I    1152
#define O    10
#define DIN  8
#define DOUT 16
#define OE   160          // O*DOUT
#define XROW 9216         // I*DIN (K of the s-GEMM, M of the g-GEMM)
#define WROW 1280         // O*DIN*DOUT (= OE*DIN, Wt row length)
#define IO   11520        // I*O
#define PSPLIT 36         // split-K partials
#define CHUNK  32         // i per spart block
#define SI     8          // i per staging round (K-window 64)
#define GRID   288        // co-resident (launch_bounds(256,2))
#define NXCD   8

#define WPREP_JOBS 720    // I*OE/256

typedef __attribute__((ext_vector_type(8))) short short8;
typedef __attribute__((ext_vector_type(4))) float floatx4;

// sc1 store: bypass per-XCD L2, lands at the coherence point (L3).
// WRITERS of cross-stage data use AS; READERS use plain loads (each buffer
// has ONE write phase before first read in-run; entry acquire fence drops
// stale lines from previous graph replays -- mechanism proven R7).
#define AS(p, v) __hip_atomic_store((p), (v), __ATOMIC_RELAXED, __HIP_MEMORY_SCOPE_AGENT)

__device__ __forceinline__ unsigned short f2bf(float f) {
    unsigned u = __builtin_bit_cast(unsigned, f);
    u += 0x7fffu + ((u >> 16) & 1u);          // RNE
    return (unsigned short)(u >> 16);
}
__device__ __forceinline__ float bf2f(unsigned short h) {
    unsigned u = ((unsigned)h) << 16;
    return __builtin_bit_cast(float, u);
}

// ---------------------------------------------------------------------------
// FULL barrier (one-time, after prep): flushes plain-stored prep outputs.
// ---------------------------------------------------------------------------
__device__ __forceinline__ void gbar_full(unsigned* cnt, unsigned* gen)
{
    __syncthreads();
    if (threadIdx.x == 0) {
        __builtin_amdgcn_fence(__ATOMIC_RELEASE, "agent");   // wbl2
        unsigned g = __hip_atomic_load(gen, __ATOMIC_RELAXED, __HIP_MEMORY_SCOPE_AGENT);
        unsigned a = __hip_atomic_fetch_add(cnt, 1u, __ATOMIC_RELAXED, __HIP_MEMORY_SCOPE_AGENT);
        if (a == GRID - 1u) {
            __hip_atomic_store(cnt, 0u, __ATOMIC_RELAXED, __HIP_MEMORY_SCOPE_AGENT);
            __hip_atomic_store(gen, g + 1u, __ATOMIC_RELAXED, __HIP_MEMORY_SCOPE_AGENT);
        } else {
            unsigned spins = 0;
            while (__hip_atomic_load(gen, __ATOMIC_RELAXED, __HIP_MEMORY_SCOPE_AGENT) == g) {
                __builtin_amdgcn_s_sleep(1);
                if (++spins > (1u << 21)) break;             // failsafe
            }
        }
        __builtin_amdgcn_fence(__ATOMIC_ACQUIRE, "agent");   // inv
    }
    __syncthreads();
}

// ---------------------------------------------------------------------------
// LIGHT barrier (steady state): no cache-wide fences (rationale as R7).
// ---------------------------------------------------------------------------
__device__ __forceinline__ void gbar_light(unsigned* cnt, unsigned* gen)
{
    __syncthreads();
    if (threadIdx.x == 0) {
        unsigned g = __hip_atomic_load(gen, __ATOMIC_RELAXED, __HIP_MEMORY_SCOPE_AGENT);
        unsigned a = __hip_atomic_fetch_add(cnt, 1u, __ATOMIC_RELAXED, __HIP_MEMORY_SCOPE_AGENT);
        if (a == GRID - 1u) {
            __hip_atomic_store(cnt, 0u, __ATOMIC_RELAXED, __HIP_MEMORY_SCOPE_AGENT);
            __hip_atomic_store(gen, g + 1u, __ATOMIC_RELEASE, __HIP_MEMORY_SCOPE_AGENT);
        } else {
            unsigned spins = 0;
            while (__hip_atomic_load(gen, __ATOMIC_RELAXED, __HIP_MEMORY_SCOPE_AGENT) == g) {
                __builtin_amdgcn_s_sleep(1);
                if (++spins > (1u << 21)) break;             // failsafe
            }
        }
    }
    __syncthreads();
}

// ---------------------------------------------------------------------------
// STAGE: prep (one-time). W -> Wt[i][oe][d] fp32; x -> xTh/xTl[(i,d)][b]
// bf16 hi/lo (g-GEMM A); x -> xh/xl[b][k] bf16 hi/lo (spart A).
// ---------------------------------------------------------------------------
__device__ __forceinline__ void stage_prep(
    int bid, int t,
    const float* __restrict__ x, const float* __restrict__ W,
    float* __restrict__ Wt,
    unsigned short* __restrict__ xTh, unsigned short* __restrict__ xTl,
    unsigned short* __restrict__ xh,  unsigned short* __restrict__ xl)
{
#pragma unroll
    for (int r = 0; r < 3; ++r) {
        int job = bid + GRID * r;
        if (job < WPREP_JOBS) {
            int g  = job * 256 + t;               // (i, oe) pair
            int i  = g / OE;
            int oe = g - i * OE;
            int o  = oe >> 4;
            int e  = oe & 15;
            const float* wp = W + (size_t)i * WROW + o * (DIN * DOUT) + e;
            float4 a, b;
            a.x = wp[0 * DOUT]; a.y = wp[1 * DOUT]; a.z = wp[2 * DOUT]; a.w = wp[3 * DOUT];
            b.x = wp[4 * DOUT]; b.y = wp[5 * DOUT]; b.z = wp[6 * DOUT]; b.w = wp[7 * DOUT];
            float4* dst = (float4*)(Wt + (size_t)g * 8);
            dst[0] = a;
            dst[1] = b;
        }
    }
#pragma unroll
    for (int r = 0; r < 4; ++r) {                 // 4*288 = 1152 jobs exactly
        int g2  = bid + GRID * r;
        int idb = g2 % 144;
        int bb  = g2 / 144;
        int id  = idb * 64 + (t & 63);            // (i,d) flat row
        int b0  = bb * 32 + (t >> 6) * 8;         // 8 batch elems per thread
        float v[8];
#pragma unroll
        for (int j = 0; j < 8; ++j)
            v[j] = x[(size_t)(b0 + j) * XROW + id];
        short8 h8, l8;
#pragma unroll
        for (int j = 0; j < 8; ++j) {
            unsigned short h = f2bf(v[j]);
            h8[j] = (short)h;
            l8[j] = (short)f2bf(v[j] - bf2f(h));
        }
        *(short8*)(xTh + (size_t)id * B + b0) = h8;
        *(short8*)(xTl + (size_t)id * B + b0) = l8;
    }
#pragma unroll
    for (int r = 0; r < 8; ++r) {                 // 8*288*256 float4 jobs
        int g = (bid + GRID * r) * 256 + t;
        float4 v = ((const float4*)x)[g];
        ushort4 h, l;
        h.x = f2bf(v.x); l.x = f2bf(v.x - bf2f(h.x));
        h.y = f2bf(v.y); l.y = f2bf(v.y - bf2f(h.y));
        h.z = f2bf(v.z); l.z = f2bf(v.z - bf2f(h.z));
        h.w = f2bf(v.w); l.w = f2bf(v.w - bf2f(h.w));
        ((ushort4*)xh)[g] = h;
        ((ushort4*)xl)[g] = l;
    }
}

// ---------------------------------------------------------------------------
// STAGE: spart. MFMA bf16 hi/lo split-K GEMM + routing prologue.
// 8-way block split per K-chunk: ic=bid>>3 (36 chunks), mb=(bid>>1)&3,
// nb=bid&1. R11: bid is the XCD-swizzled LOGICAL id, so the 8 sibling
// blocks of an ic group are co-resident on one XCD -> Wt/xh/xl redundant
// reads become local-L2 hits instead of cross-XCD HBM/L3 misses.
// ---------------------------------------------------------------------------
__device__ __forceinline__ void stage_spart(
    int bid, int t,
    unsigned short* __restrict__ Wh, unsigned short* __restrict__ Wl,
    float (*brow_s)[10], float (*cL)[10],
    const unsigned short* __restrict__ xh, const unsigned short* __restrict__ xl,
    const float* __restrict__ Wt,
    const float* __restrict__ a0, const float* __restrict__ a1,
    float* __restrict__ sp_it, int it)
{
    int ic  = bid >> 3;                           // 0..35
    int mb  = (bid >> 1) & 3;                     // 0..3
    int nb  = bid & 1;
    int b0  = mb * 64;
    int oe0 = nb * 80;
    int i0  = ic * CHUNK;

    int w    = t >> 6;
    int lane = t & 63;
    int l15  = lane & 15;
    int q    = lane >> 4;

    // routing prologue: 320 (iL,o) jobs; logits = sum of kb slices / B
    if (it) {
#pragma unroll
        for (int r = 0; r < 2; ++r) {
            int p = t + 256 * r;
            if (p < 320) {
                int iL = p / 10;
                int o  = p - iL * 10;
                int i  = i0 + iL;
                float bo = (a0[i * O + o] + a0[IO + i * O + o]) * (1.f / (float)B);
                if (it == 2)
                    bo += (a1[i * O + o] + a1[IO + i * O + o]) * (1.f / (float)B);
                brow_s[iL][o] = bo;
            }
        }
        __syncthreads();
        if (t < 32) {
            float m = brow_s[t][0];
#pragma unroll
            for (int o = 1; o < O; ++o) m = fmaxf(m, brow_s[t][o]);
            float ex[O];
            float sum = 0.f;
#pragma unroll
            for (int o = 0; o < O; ++o) { ex[o] = __expf(brow_s[t][o] - m); sum += ex[o]; }
            float inv = 1.f / sum;
#pragma unroll
            for (int o = 0; o < O; ++o) cL[t][o] = ex[o] * inv;
        }
        __syncthreads();
    }

    floatx4 acc[5];
#pragma unroll
    for (int nt = 0; nt < 5; ++nt) acc[nt] = (floatx4)(0.f);

#pragma unroll
    for (int round = 0; round < CHUNK / SI; ++round) {
        int si0 = i0 + round * SI;
        if (round) __syncthreads();

        // X fragments: plain bf16 hi/lo loads (nb-sibling shares via local L2)
        short8 ah[2], al[2];                      // [ks]
#pragma unroll
        for (int ks = 0; ks < 2; ++ks) {
            size_t goff = (size_t)(b0 + w * 16 + l15) * XROW
                        + (size_t)si0 * 8 + (ks << 5) + (q << 3);
            ah[ks] = *(const short8*)(xh + goff);
            al[ks] = *(const short8*)(xl + goff);
        }

        // stage W: coalesced loads from Wt, scale by c, split hi/lo
        // (mb-sibling redundancy now served by the shared XCD L2)
#pragma unroll
        for (int r = 0; r < 3; ++r) {
            int p = t + 256 * r;                  // (oe-local, i-local) pair
            if (p < 640) {
                int oeL = p % 80;
                int iL  = p / 80;                 // 0..7
                int o   = (oe0 + oeL) >> 4;
                const float* wp = Wt + ((size_t)(si0 + iL) * OE + oe0 + oeL) * 8;
                float cv = it ? cL[round * SI + iL][o] : 0.1f;
                float4 w0 = *(const float4*)wp;
                float4 w1 = *(const float4*)(wp + 4);
                float wv[8] = {w0.x, w0.y, w0.z, w0.w, w1.x, w1.y, w1.z, w1.w};
                short8 hv, lv;
#pragma unroll
                for (int d = 0; d < 8; ++d) {
                    float s = wv[d] * cv;
                    unsigned short h = f2bf(s);
                    hv[d] = (short)h;
                    lv[d] = (short)f2bf(s - bf2f(h));
                }
                int off = oeL * 64 + ((iL ^ (oeL & 7)) << 3);
                *(short8*)(Wh + off) = hv;
                *(short8*)(Wl + off) = lv;
            }
        }
        __syncthreads();

        // 2 K-steps of 32 over the staged window
#pragma unroll
        for (int ks = 0; ks < 2; ++ks) {
#pragma unroll
            for (int nt = 0; nt < 5; ++nt) {
                int rn  = nt * 16 + l15;
                int off = rn * 64 + ((((ks << 2) + q) ^ (rn & 7)) << 3);
                short8 bh = *(const short8*)(Wh + off);
                short8 bl = *(const short8*)(Wl + off);
                acc[nt] = __builtin_amdgcn_mfma_f32_16x16x32_bf16(ah[ks], bh, acc[nt], 0, 0, 0);
                acc[nt] = __builtin_amdgcn_mfma_f32_16x16x32_bf16(ah[ks], bl, acc[nt], 0, 0, 0);
                acc[nt] = __builtin_amdgcn_mfma_f32_16x16x32_bf16(al[ks], bh, acc[nt], 0, 0, 0);
            }
        }
    }

    // epilogue: sc1 stores of the partial tile (C/D layout m89/m91)
    float* base = sp_it + (size_t)ic * (B * OE);
    int row0 = b0 + w * 16 + q * 4;
#pragma unroll
    for (int nt = 0; nt < 5; ++nt) {
        int col = oe0 + nt * 16 + l15;
#pragma unroll
        for (int reg = 0; reg < 4; ++reg)
            AS(&base[(size_t)(row0 + reg) * OE + col], acc[nt][reg]);
    }
}

// ---------------------------------------------------------------------------
// STAGE: vred. Sum PSPLIT partials (plain scalar loads, coalesced, first-
// touch) + squash; iters 0,1 -> packed v bf16 hi|lo [oe][b] (sc1 store);
// iter 2 -> final out. 160 of 288 blocks active (physical id: all XCDs).
// ---------------------------------------------------------------------------
__device__ __forceinline__ void stage_vred(
    int bid, int t, const float* __restrict__ sp_it, float* __restrict__ out,
    unsigned* __restrict__ vT, int last)
{
    if (bid >= 160) return;
    int g = bid * 256 + t;                      // [b][o][e] flat
    float s = 0.f;
#pragma unroll 6
    for (int ic = 0; ic < PSPLIT; ++ic) s += sp_it[(size_t)ic * (B * OE) + g];

    float ss = s * s;
    ss += __shfl_xor(ss, 1, 16);
    ss += __shfl_xor(ss, 2, 16);
    ss += __shfl_xor(ss, 4, 16);
    ss += __shfl_xor(ss, 8, 16);
    float f = sqrtf(ss) / (1.f + ss);           // squash factor
    float val = s * f;

    if (last) {
        out[g] = val;
    } else {
        int b  = g / OE;
        int oe = g - b * OE;
        unsigned short h = f2bf(val);
        unsigned pack = (unsigned)h | ((unsigned)f2bf(val - bf2f(h)) << 16);
        AS(&vT[oe * B + b], pack);
    }
}

// ---------------------------------------------------------------------------
// STAGE: ggemm + in-wave agree epilogue. kb x 2 split over b (=K): 288
// blocks. R11: bid is XCD-swizzled, so the 4 siblings (nb x kb) of an m0
// group are co-resident -> xT reads shared via local L2.
// Per-kb agree slice written without atomics (summed in spart prologue).
// ---------------------------------------------------------------------------
__device__ __forceinline__ void stage_ggemm(
    int bid, int t,
    unsigned short* __restrict__ Vh, unsigned short* __restrict__ Vl,
    const unsigned short* __restrict__ xTh, const unsigned short* __restrict__ xTl,
    const unsigned* __restrict__ vT,
    const float* __restrict__ Wt, float* __restrict__ agreeP)
{
    int m0  = (bid >> 2) * 128;                   // 0..71 m-blocks
    int nb  = (bid >> 1) & 1;
    int kb  = bid & 1;
    int oe0 = nb * 80;

    int w    = t >> 6;
    int lane = t & 63;
    int l15  = lane & 15;
    int q    = lane >> 4;

    floatx4 acc[2][5];
#pragma unroll
    for (int mt = 0; mt < 2; ++mt)
#pragma unroll
        for (int nt = 0; nt < 5; ++nt) acc[mt][nt] = (floatx4)(0.f);

#pragma unroll
    for (int win = 0; win < 2; ++win) {
        int k0 = kb * 128 + win * 64;
        if (win) __syncthreads();

        // stage V window [80 oe][64 b] from packed vT, XOR-swizzled short8
#pragma unroll
        for (int r = 0; r < 3; ++r) {
            int p = t + 256 * r;
            if (p < 640) {
                int row = p >> 3;
                int ch  = p & 7;
                const unsigned* vp = vT + (size_t)(oe0 + row) * B + k0 + (ch << 3);
                uint4 u0 = *(const uint4*)vp;
                uint4 u1 = *(const uint4*)(vp + 4);
                unsigned uu[8] = {u0.x, u0.y, u0.z, u0.w, u1.x, u1.y, u1.z, u1.w};
                short8 hv, lv;
#pragma unroll
                for (int j = 0; j < 8; ++j) {
                    hv[j] = (short)(uu[j] & 0xffffu);
                    lv[j] = (short)(uu[j] >> 16);
                }
                int off = row * 64 + ((ch ^ (row & 7)) << 3);
                *(short8*)(Vh + off) = hv;
                *(short8*)(Vl + off) = lv;
            }
        }
        __syncthreads();

        // A fragments direct from xT (nb-sibling shares via local L2)
        short8 ah[2][2], al[2][2];
#pragma unroll
        for (int ks = 0; ks < 2; ++ks)
#pragma unroll
            for (int mt = 0; mt < 2; ++mt) {
                size_t ga = (size_t)(m0 + w * 32 + mt * 16 + l15) * B
                          + k0 + (ks << 5) + (q << 3);
                ah[ks][mt] = *(const short8*)(xTh + ga);
                al[ks][mt] = *(const short8*)(xTl + ga);
            }

#pragma unroll
        for (int ks = 0; ks < 2; ++ks) {
#pragma unroll
            for (int nt = 0; nt < 5; ++nt) {
                int rn  = nt * 16 + l15;
                int off = rn * 64 + ((((ks << 2) + q) ^ (rn & 7)) << 3);
                short8 bh = *(const short8*)(Vh + off);
                short8 bl = *(const short8*)(Vl + off);
#pragma unroll
                for (int mt = 0; mt < 2; ++mt) {
                    acc[mt][nt] = __builtin_amdgcn_mfma_f32_16x16x32_bf16(ah[ks][mt], bh, acc[mt][nt], 0, 0, 0);
                    acc[mt][nt] = __builtin_amdgcn_mfma_f32_16x16x32_bf16(ah[ks][mt], bl, acc[mt][nt], 0, 0, 0);
                    acc[mt][nt] = __builtin_amdgcn_mfma_f32_16x16x32_bf16(al[ks][mt], bh, acc[mt][nt], 0, 0, 0);
                }
            }
        }
    }

    // agree epilogue into this block's kb slice (no atomics)
    float* aP = agreeP + (size_t)kb * IO;
#pragma unroll
    for (int mt = 0; mt < 2; ++mt) {
        int rb = m0 + w * 32 + mt * 16 + q * 4;
        int i  = rb >> 3;
        int d0 = rb & 7;                          // 0 or 4 (q parity)
#pragma unroll
        for (int nt = 0; nt < 5; ++nt) {
            int oe = oe0 + nt * 16 + l15;
            float4 wv = *(const float4*)(Wt + (size_t)i * WROW + oe * 8 + d0);
            floatx4 a = acc[mt][nt];
            float p = a[0] * wv.x + a[1] * wv.y + a[2] * wv.z + a[3] * wv.w;
            p += __shfl_xor(p, 1);                 // e-lanes
            p += __shfl_xor(p, 2);
            p += __shfl_xor(p, 4);
            p += __shfl_xor(p, 8);
            p += __shfl_xor(p, 16);                // d-halves (q pairs)
            if ((lane & 31) == 0)
                AS(&aP[i * O + nb * 5 + nt], p);
        }
    }
}

// ---------------------------------------------------------------------------
// MEGA kernel: prep | [spart | vred | ggemm] x2 | spart | vred->out.
// R11: T1 XCD swizzle -- logical bid = (p%8)*36 + p/8 so sibling blocks
// that read the same operand panels co-reside on one XCD's L2.
// ---------------------------------------------------------------------------
__global__ __launch_bounds__(256, 2) void mega_kernel(
    const float* __restrict__ x, const float* __restrict__ W,
    float* __restrict__ out, float* __restrict__ Wt,
    unsigned short* __restrict__ xTh, unsigned short* __restrict__ xTl,
    unsigned short* __restrict__ xh,  unsigned short* __restrict__ xl,
    unsigned* __restrict__ vT0, unsigned* __restrict__ vT1,
    float* __restrict__ sbuf, float* __restrict__ a0, float* __restrict__ a1,
    unsigned* __restrict__ bar)
{
    __shared__ unsigned short Sh[80 * 64], Sl[80 * 64];   // spart & ggemm reuse
    __shared__ float brow_s[32][10];
    __shared__ float cL[32][10];

    unsigned* cnt = bar;            // cacheline 0
    unsigned* gen = bar + 32;       // cacheline 1
    int p   = blockIdx.x;
    int bid = (p % NXCD) * (GRID / NXCD) + p / NXCD;   // T1 swizzle (288%8==0)
    int t   = threadIdx.x;

    // entry acquire: drop clean L2 lines left by PREVIOUS runs of this kernel
    if (t == 0) __builtin_amdgcn_fence(__ATOMIC_ACQUIRE, "agent");
    __syncthreads();

    stage_prep(p, t, x, W, Wt, xTh, xTl, xh, xl);
    gbar_full(cnt, gen);            // one-time: flush plain-stored prep data

    for (int it = 0; it < 3; ++it) {
        float* sp_it = sbuf + (size_t)it * PSPLIT * (B * OE);
        unsigned* vT = (it == 0) ? vT0 : vT1;
        stage_spart(bid, t, Sh, Sl, brow_s, cL, xh, xl, Wt, a0, a1, sp_it, it);
        gbar_light(cnt, gen);
        stage_vred(p, t, sp_it, out, vT, it == 2);
        if (it == 2) break;
        gbar_light(cnt, gen);
        stage_ggemm(bid, t, Sh, Sl, xTh, xTl, vT, Wt, it == 0 ? a0 : a1);
        gbar_light(cnt, gen);
    }
}

// ---------------------------------------------------------------------------
extern "C" void kernel_launch(void* const* d_in, const int* in_sizes, int n_in,
                              void* d_out, int out_size, void* d_ws, size_t ws_size,
                              hipStream_t stream)
{
    const float* x = (const float*)d_in[0];   // [256,1152,8]
    const float* W = (const float*)d_in[1];   // [1152,10,8,16]
    float* out = (float*)d_out;               // [256,10,16,1] flat = 40960

    // ws: bar 256B | a0 2*IO | a1 2*IO | Wt 5.9MB | sp[3] 17.7MB |
    //     xTh/xTl 9.4MB | xh/xl 9.4MB | vT0/vT1 320KB   (~43 MB of 256 MB)
    unsigned* bar = (unsigned*)d_ws;
    float* a0   = (float*)((char*)d_ws + 256);
    float* a1   = a0 + 2 * IO;
    float* Wt   = a1 + 2 * IO;
    float* sbuf = Wt + (size_t)I * OE * DIN;
    unsigned short* xTh = (unsigned short*)(sbuf + (size_t)3 * PSPLIT * B * OE);
    unsigned short* xTl = xTh + (size_t)XROW * B;
    unsigned short* xh  = xTl + (size_t)XROW * B;
    unsigned short* xl  = xh  + (size_t)XROW * B;
    unsigned* vT0       = (unsigned*)(xl + (size_t)XROW * B);
    unsigned* vT1       = vT0 + B * OE;

    // zero barrier state (memset node is graph-capture legal)
    hipMemsetAsync(d_ws, 0, 256, stream);

    mega_kernel<<<GRID, 256, 0, stream>>>(
        x, W, out, Wt, xTh, xTl, xh, xl, vT0, vT1, sbuf, a0, a1, bar);
}